// Round 8
// baseline (565.861 us; speedup 1.0000x reference)
//
#include <hip/hip_runtime.h>

typedef unsigned int u32;
typedef unsigned short u16;
typedef __attribute__((ext_vector_type(8))) short bf16x8;
typedef __attribute__((ext_vector_type(4))) float f32x4;

#define B_   512
#define L_   201
#define T_   200
#define H_   128
#define V_   100001
#define G3_  384
#define M_   (B_*T_)         // 102400
#define GPB  16              // batches per recurrence block
#define NBLK (B_/GPB)        // 32 blocks
#define HS   136             // LDS row stride in u16 (>=128!), 272B, 16B-aligned

// ws layout (bytes):
//   [0,256) flag | [256,+25.6MB) embT | [25600768,+78.6MB) gi2 | [104243968,+26.2MB) hseq2
// gi2  (wave-major): off_u16 = (grp*T+t)*6144 + g*2048 + w*256 + q*64 + u*4   (78,643,200 B)
// hseq2(wave-major): off_u16 = (grp*T+t)*2048 +           w*256 + q*64 + u*4  (26,214,400 B)
#define OFF_EMBT 256
#define OFF_GI   25600768ull
#define OFF_HSEQ 104243968ull

__device__ __forceinline__ float bf2f(u16 a) {
    return __uint_as_float(((u32)a) << 16);
}
__device__ __forceinline__ void bf2x2(u32 p, float& lo, float& hi) {
    lo = __uint_as_float(p << 16);
    hi = __uint_as_float(p & 0xffff0000u);
}
__device__ __forceinline__ u16 f2bf(float f) {
    u32 u = __float_as_uint(f);
    u32 lsb = (u >> 16) & 1u;
    u += 0x7fffu + lsb;   // RNE
    return (u16)(u >> 16);
}
__device__ __forceinline__ u32 packbf(float a, float b) {
    return (u32)f2bf(a) | ((u32)f2bf(b) << 16);
}
__device__ __forceinline__ float sigmoidf_(float x) {
    return 1.0f / (1.0f + __expf(-x));
}
__device__ __forceinline__ float tanhf_(float x) {
    float e = __expf(2.0f * x);
    return 1.0f - 2.0f / (e + 1.0f);
}
__device__ __forceinline__ void halfred2(float& a, float& b) {
    #pragma unroll
    for (int o = 1; o <= 16; o <<= 1) {
        a += __shfl_xor(a, o, 64);
        b += __shfl_xor(b, o, 64);
    }
}
__device__ __forceinline__ float ldv(const void* p, int dt, int i) {
    return dt ? ((const float*)p)[i] : bf2f(((const u16*)p)[i]);
}
// LDS-only barrier: waits ds ops but does NOT drain vmcnt.
__device__ __forceinline__ void ldsbar() {
    asm volatile("s_waitcnt lgkmcnt(0)\n\ts_barrier" ::: "memory");
}
__device__ __forceinline__ bf16x8 load_frag(const void* W, int dt, int row, int koff) {
    union { bf16x8 v; u32 uu[4]; uint4 q; } r;
    if (dt) {
        const float4* p = (const float4*)((const float*)W + (size_t)row * H_ + koff);
        const float4 a = p[0], b = p[1];
        r.uu[0] = packbf(a.x, a.y); r.uu[1] = packbf(a.z, a.w);
        r.uu[2] = packbf(b.x, b.y); r.uu[3] = packbf(b.z, b.w);
    } else {
        r.q = *(const uint4*)((const u16*)W + (size_t)row * H_ + koff);
    }
    return r.v;
}
#define MFMA16(a, b, c) __builtin_amdgcn_mfma_f32_16x16x32_bf16((a), (b), (c), 0, 0, 0)

// ---------------- K0: dtype sniffer --------------------------------------------
__global__ __launch_bounds__(64) void k_sniff(const u32* __restrict__ raw,
                                              int* __restrict__ flag) {
    const int lane = threadIdx.x;
    int big = 0;
    #pragma unroll
    for (int i = 0; i < 16; i++) {
        const u32 w = raw[lane * 16 + i];
        float lo, hi; bf2x2(w, lo, hi);
        if (!(fabsf(lo) <= 16.0f)) big++;
        if (!(fabsf(hi) <= 16.0f)) big++;
    }
    #pragma unroll
    for (int o = 32; o >= 1; o >>= 1) big += __shfl_xor(big, o, 64);
    if (lane == 0) *flag = (big > 8) ? 1 : 0;
}

// ---------------- K1: transpose emb_W (H,V) -> embT (V,H) bf16 ------------------
__global__ __launch_bounds__(1024) void k_transpose(const void* __restrict__ embW,
                                                    u16* __restrict__ embT,
                                                    const int* __restrict__ flag) {
    const int dt = *flag;
    __shared__ u16 tile[32][33];
    const int v0 = blockIdx.x * 32;
    const int h0 = blockIdx.y * 32;
    const int tx = threadIdx.x, ty = threadIdx.y;
    const int v = v0 + tx, h = h0 + ty;
    if (v < V_) {
        u16 val;
        if (dt) val = f2bf(((const float*)embW)[(size_t)h * V_ + v]);
        else    val = ((const u16*)embW)[(size_t)h * V_ + v];
        tile[ty][tx] = val;
    }
    __syncthreads();
    const int vo = v0 + ty, ho = h0 + tx;
    if (vo < V_) embT[(size_t)vo * H_ + ho] = tile[tx][ty];
}

// ---------------- K2: k_gi — gather + LN1 + (gi = x @ Wih^T + bih), MFMA --------
// 1600 blocks x 256 threads. Writes gi2 in k_rec's wave-major coalesced layout.
__global__ __launch_bounds__(256, 2) void k_gi(const int* __restrict__ seqs,
                                               const u16* __restrict__ embT,
                                               const void* __restrict__ g1,
                                               const void* __restrict__ b1,
                                               const void* __restrict__ Wih,
                                               const void* __restrict__ bih,
                                               u16* __restrict__ gi2,
                                               const int* __restrict__ flag) {
    const int dt = *flag;
    __shared__ u16 xs[64 * HS];       // LN1(x) rows, bf16
    const int tid = threadIdx.x;
    const int w = tid >> 6, L = tid & 63;
    const int q = L >> 4, u = L & 15;
    const int lk = L & 31;
    const int hw = w * 2 + (L >> 5);  // half-wave id 0..7
    const int m0 = blockIdx.x * 64;
    float g1v[4], b1v[4];
    #pragma unroll
    for (int j = 0; j < 4; j++) {
        g1v[j] = ldv(g1, dt, lk * 4 + j);
        b1v[j] = ldv(b1, dt, lk * 4 + j);
    }
    // stage: gather + LN1 -> xs (bf16)
    #pragma unroll
    for (int it = 0; it < 8; it++) {
        const int row = hw * 8 + it;
        const int m = m0 + row;
        const int b = m / T_, t = m - b * T_;
        const int tok = seqs[b * L_ + t];
        const uint2 e = *(const uint2*)&embT[(size_t)tok * H_ + lk * 4];
        float f0, f1, f2, f3; bf2x2(e.x, f0, f1); bf2x2(e.y, f2, f3);
        float s1 = (f0 + f1) + (f2 + f3);
        float s2 = (f0*f0 + f1*f1) + (f2*f2 + f3*f3);
        halfred2(s1, s2);
        const float mu = s1 * (1.0f / H_);
        const float rs = rsqrtf(s2 * (1.0f / H_) - mu * mu + 1e-8f);
        uint2 xw;
        xw.x = packbf((f0-mu)*rs*g1v[0]+b1v[0], (f1-mu)*rs*g1v[1]+b1v[1]);
        xw.y = packbf((f2-mu)*rs*g1v[2]+b1v[2], (f3-mu)*rs*g1v[3]+b1v[3]);
        *(uint2*)&xs[row * HS + lk * 4] = xw;
    }
    // Wih A-frags for this wave's 6 N-tiles -> registers
    bf16x8 af[6][4];
    float bb[6][4];
    #pragma unroll
    for (int j = 0; j < 6; j++) {
        const int nt = w * 6 + j;
        #pragma unroll
        for (int c = 0; c < 4; c++)
            af[j][c] = load_frag(Wih, dt, nt * 16 + u, c * 32 + q * 8);
        if (dt) {
            const float4 bv = *(const float4*)((const float*)bih + nt * 16 + q * 4);
            bb[j][0] = bv.x; bb[j][1] = bv.y; bb[j][2] = bv.z; bb[j][3] = bv.w;
        } else {
            const uint2 bv = *(const uint2*)((const u16*)bih + nt * 16 + q * 4);
            bf2x2(bv.x, bb[j][0], bb[j][1]); bf2x2(bv.y, bb[j][2], bb[j][3]);
        }
    }
    ldsbar();
    #pragma unroll
    for (int s = 0; s < 4; s++) {
        bf16x8 xbv[4];
        #pragma unroll
        for (int c = 0; c < 4; c++)
            xbv[c] = *(const bf16x8*)&xs[(s * 16 + u) * HS + c * 32 + q * 8];
        const int m = m0 + s * 16 + u;
        const int b = m / T_, t = m - b * T_;
        const int grp = b >> 4, bi = b & 15;
        const size_t base_mt = (size_t)(grp * T_ + t) * 6144 + q * 64 + bi * 4;
        #pragma unroll
        for (int j = 0; j < 6; j++) {
            const int nt = w * 6 + j;
            f32x4 C = {0.f, 0.f, 0.f, 0.f};
            #pragma unroll
            for (int c = 0; c < 4; c++) C = MFMA16(af[j][c], xbv[c], C);
            uint2 o;
            o.x = packbf(C[0] + bb[j][0], C[1] + bb[j][1]);
            o.y = packbf(C[2] + bb[j][2], C[3] + bb[j][3]);
            *(uint2*)&gi2[base_mt + (nt >> 3) * 2048 + (nt & 7) * 256] = o;
        }
    }
}

// ---------------- K3: k_rec — slim persistent GRU recurrence --------------------
// 32 blocks x 512 threads (8 waves), 256-VGPR budget (2 waves/SIMD).
// Per step: 3 coalesced 512B/wave gi loads (prefetch 2 ahead), 4 ds_read_b128,
// 12 MFMA (2-deep chains), gate VALU, coalesced h store. One LDS-only barrier.
__global__ __launch_bounds__(512, 2) void k_rec(const u16* __restrict__ gi2,
                                                const void* __restrict__ Whh,
                                                const void* __restrict__ bhh,
                                                u16* __restrict__ hseq2,
                                                const int* __restrict__ flag) {
    const int dt = *flag;
    __shared__ u16 hbuf[2][GPB * HS];
    const int tid = threadIdx.x;
    const int w = tid >> 6, L = tid & 63;
    const int q = L >> 4, u = L & 15;
    const int grp = blockIdx.x;
    for (int i = tid; i < GPB * HS; i += 512) hbuf[0][i] = 0;
    bf16x8 wa[12];
    #pragma unroll
    for (int g = 0; g < 3; g++)
        #pragma unroll
        for (int c = 0; c < 4; c++)
            wa[g * 4 + c] = load_frag(Whh, dt, g * H_ + w * 16 + u, c * 32 + q * 8);
    float sbr[4], sbz[4], bhn[4];
    #pragma unroll
    for (int r = 0; r < 4; r++) {
        const int i = w * 16 + q * 4 + r;
        sbr[r] = ldv(bhh, dt, i);
        sbz[r] = ldv(bhh, dt, H_ + i);
        bhn[r] = ldv(bhh, dt, 2 * H_ + i);
    }
    float hst[4] = {0.f, 0.f, 0.f, 0.f};
    const u16* gp = gi2 + (size_t)grp * T_ * 6144 + (size_t)w * 256 + q * 64 + u * 4;
    u16* hp = hseq2 + (size_t)grp * T_ * 2048 + (size_t)w * 256 + q * 64 + u * 4;
    uint2 gcur[3], gnxt[3];
    #pragma unroll
    for (int g = 0; g < 3; g++) {
        gcur[g] = *(const uint2*)(gp + 0 * 6144 + g * 2048);
        gnxt[g] = *(const uint2*)(gp + 1 * 6144 + g * 2048);
    }
    ldsbar();
    for (int t = 0; t < T_; t++) {
        const int cur = t & 1;
        const int tpre = (t + 2 < T_) ? (t + 2) : (T_ - 1);   // branchless prefetch
        uint2 g2s[3];
        #pragma unroll
        for (int g = 0; g < 3; g++)
            g2s[g] = *(const uint2*)(gp + (size_t)tpre * 6144 + g * 2048);
        bf16x8 hbv[4];
        #pragma unroll
        for (int c = 0; c < 4; c++)
            hbv[c] = *(const bf16x8*)&hbuf[cur][u * HS + c * 32 + q * 8];
        f32x4 z4 = {0.f, 0.f, 0.f, 0.f};
        f32x4 gr0 = z4, gr1 = z4, gz0 = z4, gz1 = z4, gn0 = z4, gn1 = z4;
        gr0 = MFMA16(wa[0], hbv[0], gr0);  gr0 = MFMA16(wa[1], hbv[1], gr0);
        gr1 = MFMA16(wa[2], hbv[2], gr1);  gr1 = MFMA16(wa[3], hbv[3], gr1);
        gz0 = MFMA16(wa[4], hbv[0], gz0);  gz0 = MFMA16(wa[5], hbv[1], gz0);
        gz1 = MFMA16(wa[6], hbv[2], gz1);  gz1 = MFMA16(wa[7], hbv[3], gz1);
        gn0 = MFMA16(wa[8], hbv[0], gn0);  gn0 = MFMA16(wa[9], hbv[1], gn0);
        gn1 = MFMA16(wa[10], hbv[2], gn1); gn1 = MFMA16(wa[11], hbv[3], gn1);
        float gir[4], giz[4], gin[4];
        bf2x2(gcur[0].x, gir[0], gir[1]); bf2x2(gcur[0].y, gir[2], gir[3]);
        bf2x2(gcur[1].x, giz[0], giz[1]); bf2x2(gcur[1].y, giz[2], giz[3]);
        bf2x2(gcur[2].x, gin[0], gin[1]); bf2x2(gcur[2].y, gin[2], gin[3]);
        float hpv[4];
        #pragma unroll
        for (int r = 0; r < 4; r++) {
            const float rr = sigmoidf_(gir[r] + (gr0[r] + gr1[r]) + sbr[r]);
            const float zz = sigmoidf_(giz[r] + (gz0[r] + gz1[r]) + sbz[r]);
            const float nn = tanhf_(gin[r] + rr * ((gn0[r] + gn1[r]) + bhn[r]));
            const float hn = (1.f - zz) * nn + zz * hst[r];
            hst[r] = hn; hpv[r] = hn;
        }
        uint2 hw2;
        hw2.x = packbf(hpv[0], hpv[1]);
        hw2.y = packbf(hpv[2], hpv[3]);
        *(uint2*)&hbuf[cur ^ 1][u * HS + w * 16 + q * 4] = hw2;
        *(uint2*)(hp + (size_t)t * 2048) = hw2;      // coalesced 512B/wave
        gcur[0] = gnxt[0]; gcur[1] = gnxt[1]; gcur[2] = gnxt[2];
        gnxt[0] = g2s[0];  gnxt[1] = g2s[1];  gnxt[2] = g2s[2];
        ldsbar();
    }
}

// ---------------- K4: k_dot — LN2 + pos/neg dots, fully parallel ----------------
__global__ __launch_bounds__(256) void k_dot(const int* __restrict__ seqs,
                                             const int* __restrict__ negs,
                                             const u16* __restrict__ hseq2,
                                             const u16* __restrict__ embT,
                                             const void* __restrict__ g2,
                                             const void* __restrict__ b2,
                                             void* __restrict__ out,
                                             const int* __restrict__ flag) {
    const int dt = *flag;
    const int m = blockIdx.x * 4 + (threadIdx.x >> 6);
    const int L = threadIdx.x & 63;
    const int b = m / T_, t = m - b * T_;
    const int grp = b >> 4, bi = b & 15;
    // h elements 2L, 2L+1 from wave-major hseq2
    const size_t hoff = (size_t)(grp * T_ + t) * 2048
                      + (size_t)(L >> 3) * 256 + ((L >> 1) & 3) * 64 + bi * 4 + (L & 1) * 2;
    const u32 hh = *(const u32*)&hseq2[hoff];
    float h0, h1; bf2x2(hh, h0, h1);
    float s1 = h0 + h1, s2 = h0 * h0 + h1 * h1;
    #pragma unroll
    for (int o = 1; o <= 32; o <<= 1) {
        s1 += __shfl_xor(s1, o, 64);
        s2 += __shfl_xor(s2, o, 64);
    }
    const float mu = s1 * (1.0f / H_);
    const float rs = rsqrtf(s2 * (1.0f / H_) - mu * mu + 1e-8f);
    float gv0, gv1, bv0, bv1;
    if (dt) {
        const float2 g = ((const float2*)g2)[L];
        const float2 bb = ((const float2*)b2)[L];
        gv0 = g.x; gv1 = g.y; bv0 = bb.x; bv1 = bb.y;
    } else {
        bf2x2(((const u32*)g2)[L], gv0, gv1);
        bf2x2(((const u32*)b2)[L], bv0, bv1);
    }
    const float lo0 = (h0 - mu) * rs * gv0 + bv0;
    const float lo1 = (h1 - mu) * rs * gv1 + bv1;
    const int ptok = seqs[b * L_ + t + 1];
    const int ntok = negs[b * L_ + t + 1];
    const u32 pp = *(const u32*)&embT[(size_t)ptok * H_ + L * 2];
    const u32 nn = *(const u32*)&embT[(size_t)ntok * H_ + L * 2];
    float p0, p1, n0, n1; bf2x2(pp, p0, p1); bf2x2(nn, n0, n1);
    float pe = lo0 * p0 + lo1 * p1;
    float ne = lo0 * n0 + lo1 * n1;
    #pragma unroll
    for (int o = 1; o <= 32; o <<= 1) {
        pe += __shfl_xor(pe, o, 64);
        ne += __shfl_xor(ne, o, 64);
    }
    if (L == 0) {
        if (dt) {
            ((float*)out)[m]      = pe;
            ((float*)out)[M_ + m] = ne;
        } else {
            ((u16*)out)[m]        = f2bf(pe);
            ((u16*)out)[M_ + m]   = f2bf(ne);
        }
    }
}

extern "C" void kernel_launch(void* const* d_in, const int* in_sizes, int n_in,
                              void* d_out, int out_size, void* d_ws, size_t ws_size,
                              hipStream_t stream) {
    const int* seqs = (const int*)d_in[0];
    const int* negs = (const int*)d_in[1];
    const void* embW = d_in[2];
    const void* Wih  = d_in[3];
    const void* Whh  = d_in[4];
    const void* bih  = d_in[5];
    const void* bhh  = d_in[6];
    const void* g1   = d_in[7];
    const void* b1   = d_in[8];
    const void* g2   = d_in[9];
    const void* b2   = d_in[10];

    char* ws = (char*)d_ws;
    int* flag = (int*)ws;
    u16* embT  = (u16*)(ws + OFF_EMBT);
    u16* gi2   = (u16*)(ws + OFF_GI);
    u16* hseq2 = (u16*)(ws + OFF_HSEQ);

    k_sniff<<<1, 64, 0, stream>>>((const u32*)embW, flag);
    k_transpose<<<dim3((V_ + 31) / 32, H_ / 32), dim3(32, 32), 0, stream>>>(embW, embT, flag);
    k_gi<<<M_ / 64, 256, 0, stream>>>(seqs, embT, g1, b1, Wih, bih, gi2, flag);
    k_rec<<<NBLK, 512, 0, stream>>>(gi2, Whh, bhh, hseq2, flag);
    k_dot<<<M_ / 4, 256, 0, stream>>>(seqs, negs, hseq2, embT, g2, b2, d_out, flag);
}

// Round 9
// 381.220 us; speedup vs baseline: 1.4843x; 1.4843x over previous
//
#include <hip/hip_runtime.h>

typedef unsigned int u32;
typedef unsigned short u16;
typedef __attribute__((ext_vector_type(8))) short bf16x8;
typedef __attribute__((ext_vector_type(4))) float f32x4;

#define B_   512
#define L_   201
#define T_   200
#define H_   128
#define V_   100001
#define G3_  384
#define M_   (B_*T_)         // 102400
#define GPB  16              // batches per recurrence block
#define NBLK (B_/GPB)        // 32 blocks
#define HS   136             // LDS row stride in u16 (>=128!), 272B, 16B-aligned

// ws layout (bytes):
//   [0,256) flag | [256,+25.6MB) embT | [25600768,+78.6MB) gi2 | [104243968,+26.2MB) hseq2
// gi2  (wave-major): off_u16 = (grp*T+t)*6144 + g*2048 + w*256 + q*64 + u*4
// hseq2(wave-major): off_u16 = (grp*T+t)*2048 +           w*256 + q*64 + u*4
#define OFF_EMBT 256
#define OFF_GI   25600768ull
#define OFF_HSEQ 104243968ull

__device__ __forceinline__ float bf2f(u16 a) {
    return __uint_as_float(((u32)a) << 16);
}
__device__ __forceinline__ void bf2x2(u32 p, float& lo, float& hi) {
    lo = __uint_as_float(p << 16);
    hi = __uint_as_float(p & 0xffff0000u);
}
__device__ __forceinline__ u16 f2bf(float f) {
    u32 u = __float_as_uint(f);
    u32 lsb = (u >> 16) & 1u;
    u += 0x7fffu + lsb;   // RNE
    return (u16)(u >> 16);
}
__device__ __forceinline__ u32 packbf(float a, float b) {
#if __has_builtin(__builtin_amdgcn_cvt_pk_bf16_f32)
    typedef __attribute__((ext_vector_type(2))) __bf16 bf16x2_t;
    bf16x2_t r = __builtin_amdgcn_cvt_pk_bf16_f32(a, b);
    return *(u32*)&r;
#else
    return (u32)f2bf(a) | ((u32)f2bf(b) << 16);
#endif
}
__device__ __forceinline__ float frcp(float x) {
    return __builtin_amdgcn_rcpf(x);   // v_rcp_f32, ~1ulp
}
__device__ __forceinline__ float sigmoidf_(float x) {
    return frcp(1.0f + __expf(-x));
}
__device__ __forceinline__ float tanhf_(float x) {
    return 1.0f - 2.0f * frcp(__expf(2.0f * x) + 1.0f);
}
__device__ __forceinline__ void halfred2(float& a, float& b) {
    #pragma unroll
    for (int o = 1; o <= 16; o <<= 1) {
        a += __shfl_xor(a, o, 64);
        b += __shfl_xor(b, o, 64);
    }
}
__device__ __forceinline__ float ldv(const void* p, int dt, int i) {
    return dt ? ((const float*)p)[i] : bf2f(((const u16*)p)[i]);
}
// LDS-only barrier: waits ds ops but does NOT drain vmcnt.
__device__ __forceinline__ void ldsbar() {
    asm volatile("s_waitcnt lgkmcnt(0)\n\ts_barrier" ::: "memory");
}
__device__ __forceinline__ bf16x8 load_frag(const void* W, int dt, int row, int koff) {
    union { bf16x8 v; u32 uu[4]; uint4 q; } r;
    if (dt) {
        const float4* p = (const float4*)((const float*)W + (size_t)row * H_ + koff);
        const float4 a = p[0], b = p[1];
        r.uu[0] = packbf(a.x, a.y); r.uu[1] = packbf(a.z, a.w);
        r.uu[2] = packbf(b.x, b.y); r.uu[3] = packbf(b.z, b.w);
    } else {
        r.q = *(const uint4*)((const u16*)W + (size_t)row * H_ + koff);
    }
    return r.v;
}
#define MFMA16(a, b, c) __builtin_amdgcn_mfma_f32_16x16x32_bf16((a), (b), (c), 0, 0, 0)

// ---------------- K0: dtype sniffer --------------------------------------------
__global__ __launch_bounds__(64) void k_sniff(const u32* __restrict__ raw,
                                              int* __restrict__ flag) {
    const int lane = threadIdx.x;
    int big = 0;
    #pragma unroll
    for (int i = 0; i < 16; i++) {
        const u32 w = raw[lane * 16 + i];
        float lo, hi; bf2x2(w, lo, hi);
        if (!(fabsf(lo) <= 16.0f)) big++;
        if (!(fabsf(hi) <= 16.0f)) big++;
    }
    #pragma unroll
    for (int o = 32; o >= 1; o <<= 1) big += __shfl_xor(big, o, 64);
    if (lane == 0) *flag = (big > 8) ? 1 : 0;
}

// ---------------- K1: transpose emb_W (H,V) -> embT (V,H) bf16 ------------------
__global__ __launch_bounds__(1024) void k_transpose(const void* __restrict__ embW,
                                                    u16* __restrict__ embT,
                                                    const int* __restrict__ flag) {
    const int dt = *flag;
    __shared__ u16 tile[32][33];
    const int v0 = blockIdx.x * 32;
    const int h0 = blockIdx.y * 32;
    const int tx = threadIdx.x, ty = threadIdx.y;
    const int v = v0 + tx, h = h0 + ty;
    if (v < V_) {
        u16 val;
        if (dt) val = f2bf(((const float*)embW)[(size_t)h * V_ + v]);
        else    val = ((const u16*)embW)[(size_t)h * V_ + v];
        tile[ty][tx] = val;
    }
    __syncthreads();
    const int vo = v0 + ty, ho = h0 + tx;
    if (vo < V_) embT[(size_t)vo * H_ + ho] = tile[tx][ty];
}

// ---------------- K2: k_gi — gather + LN1 + (gi = x @ Wih^T + bih), MFMA --------
// 1600 blocks x 256 threads. Block tile = 16 batches x 4 timesteps -> MFMA C
// cols are batches at fixed t, so the gi2 wave-major store is one contiguous
// 512B/wave transaction (exactly the layout k_rec reads).
__global__ __launch_bounds__(256) void k_gi(const int* __restrict__ seqs,
                                            const u16* __restrict__ embT,
                                            const void* __restrict__ g1,
                                            const void* __restrict__ b1,
                                            const void* __restrict__ Wih,
                                            const void* __restrict__ bih,
                                            u16* __restrict__ gi2,
                                            const int* __restrict__ flag) {
    const int dt = *flag;
    __shared__ u16 xs[64 * HS];       // LN1(x) rows, row = s*16 + bi
    const int tid = threadIdx.x;
    const int w = tid >> 6, L = tid & 63;
    const int q = L >> 4, u = L & 15;
    const int lk = L & 31;
    const int hw = w * 2 + (L >> 5);  // half-wave id 0..7
    const int grp = blockIdx.x / 50;  // batch group 0..31
    const int tc  = blockIdx.x % 50;  // t-chunk (4 steps)
    float g1v[4], b1v[4];
    #pragma unroll
    for (int j = 0; j < 4; j++) {
        g1v[j] = ldv(g1, dt, lk * 4 + j);
        b1v[j] = ldv(b1, dt, lk * 4 + j);
    }
    // stage: gather + LN1 -> xs (bf16); row = s*16 + bi
    #pragma unroll
    for (int it = 0; it < 8; it++) {
        const int row = hw * 8 + it;
        const int s = row >> 4, bi = row & 15;
        const int b = grp * GPB + bi;
        const int t = tc * 4 + s;
        const int tok = seqs[b * L_ + t];
        const uint2 e = *(const uint2*)&embT[(size_t)tok * H_ + lk * 4];
        float f0, f1, f2, f3; bf2x2(e.x, f0, f1); bf2x2(e.y, f2, f3);
        float s1 = (f0 + f1) + (f2 + f3);
        float s2 = (f0*f0 + f1*f1) + (f2*f2 + f3*f3);
        halfred2(s1, s2);
        const float mu = s1 * (1.0f / H_);
        const float rs = rsqrtf(s2 * (1.0f / H_) - mu * mu + 1e-8f);
        uint2 xw;
        xw.x = packbf((f0-mu)*rs*g1v[0]+b1v[0], (f1-mu)*rs*g1v[1]+b1v[1]);
        xw.y = packbf((f2-mu)*rs*g1v[2]+b1v[2], (f3-mu)*rs*g1v[3]+b1v[3]);
        *(uint2*)&xs[row * HS + lk * 4] = xw;
    }
    // Wih A-frags for this wave's 6 N-tiles -> registers
    bf16x8 af[6][4];
    float bb[6][4];
    #pragma unroll
    for (int j = 0; j < 6; j++) {
        const int nt = w * 6 + j;
        #pragma unroll
        for (int c = 0; c < 4; c++)
            af[j][c] = load_frag(Wih, dt, nt * 16 + u, c * 32 + q * 8);
        if (dt) {
            const float4 bv = *(const float4*)((const float*)bih + nt * 16 + q * 4);
            bb[j][0] = bv.x; bb[j][1] = bv.y; bb[j][2] = bv.z; bb[j][3] = bv.w;
        } else {
            const uint2 bv = *(const uint2*)((const u16*)bih + nt * 16 + q * 4);
            bf2x2(bv.x, bb[j][0], bb[j][1]); bf2x2(bv.y, bb[j][2], bb[j][3]);
        }
    }
    ldsbar();
    #pragma unroll
    for (int s = 0; s < 4; s++) {
        bf16x8 xbv[4];
        #pragma unroll
        for (int c = 0; c < 4; c++)
            xbv[c] = *(const bf16x8*)&xs[(s * 16 + u) * HS + c * 32 + q * 8];
        const int t = tc * 4 + s;
        const size_t base_t = (size_t)(grp * T_ + t) * 6144 + q * 64 + u * 4;
        #pragma unroll
        for (int j = 0; j < 6; j++) {
            const int nt = w * 6 + j;
            f32x4 C = {0.f, 0.f, 0.f, 0.f};
            #pragma unroll
            for (int c = 0; c < 4; c++) C = MFMA16(af[j][c], xbv[c], C);
            uint2 o;
            o.x = packbf(C[0] + bb[j][0], C[1] + bb[j][1]);
            o.y = packbf(C[2] + bb[j][2], C[3] + bb[j][3]);
            // coalesced: lanes (q,u) cover q*64+u*4 -> contiguous 512B/wave
            *(uint2*)&gi2[base_t + (nt >> 3) * 2048 + (nt & 7) * 256] = o;
        }
    }
}

// ---------------- K3: k_rec — slim persistent GRU recurrence --------------------
// 32 blocks x 512 threads (8 waves). Per step: 3 coalesced gi loads (prefetch 2
// ahead), 4 ds_read_b128, 12 MFMA, gate VALU (rcp-based), coalesced h store.
__global__ __launch_bounds__(512, 2) void k_rec(const u16* __restrict__ gi2,
                                                const void* __restrict__ Whh,
                                                const void* __restrict__ bhh,
                                                u16* __restrict__ hseq2,
                                                const int* __restrict__ flag) {
    const int dt = *flag;
    __shared__ u16 hbuf[2][GPB * HS];
    const int tid = threadIdx.x;
    const int w = tid >> 6, L = tid & 63;
    const int q = L >> 4, u = L & 15;
    const int grp = blockIdx.x;
    for (int i = tid; i < GPB * HS; i += 512) hbuf[0][i] = 0;
    bf16x8 wa[12];
    #pragma unroll
    for (int g = 0; g < 3; g++)
        #pragma unroll
        for (int c = 0; c < 4; c++)
            wa[g * 4 + c] = load_frag(Whh, dt, g * H_ + w * 16 + u, c * 32 + q * 8);
    float sbr[4], sbz[4], bhn[4];
    #pragma unroll
    for (int r = 0; r < 4; r++) {
        const int i = w * 16 + q * 4 + r;
        sbr[r] = ldv(bhh, dt, i);
        sbz[r] = ldv(bhh, dt, H_ + i);
        bhn[r] = ldv(bhh, dt, 2 * H_ + i);
    }
    float hst[4] = {0.f, 0.f, 0.f, 0.f};
    const u16* gp = gi2 + (size_t)grp * T_ * 6144 + (size_t)w * 256 + q * 64 + u * 4;
    u16* hp = hseq2 + (size_t)grp * T_ * 2048 + (size_t)w * 256 + q * 64 + u * 4;
    uint2 gcur[3], gnxt[3];
    #pragma unroll
    for (int g = 0; g < 3; g++) {
        gcur[g] = *(const uint2*)(gp + 0 * 6144 + g * 2048);
        gnxt[g] = *(const uint2*)(gp + 1 * 6144 + g * 2048);
    }
    ldsbar();
    for (int t = 0; t < T_; t++) {
        const int cur = t & 1;
        const int tpre = (t + 2 < T_) ? (t + 2) : (T_ - 1);   // branchless prefetch
        uint2 g2s[3];
        #pragma unroll
        for (int g = 0; g < 3; g++)
            g2s[g] = *(const uint2*)(gp + (size_t)tpre * 6144 + g * 2048);
        bf16x8 hbv[4];
        #pragma unroll
        for (int c = 0; c < 4; c++)
            hbv[c] = *(const bf16x8*)&hbuf[cur][u * HS + c * 32 + q * 8];
        f32x4 z4 = {0.f, 0.f, 0.f, 0.f};
        f32x4 gr0 = z4, gr1 = z4, gz0 = z4, gz1 = z4, gn0 = z4, gn1 = z4;
        gr0 = MFMA16(wa[0], hbv[0], gr0);  gr0 = MFMA16(wa[1], hbv[1], gr0);
        gr1 = MFMA16(wa[2], hbv[2], gr1);  gr1 = MFMA16(wa[3], hbv[3], gr1);
        gz0 = MFMA16(wa[4], hbv[0], gz0);  gz0 = MFMA16(wa[5], hbv[1], gz0);
        gz1 = MFMA16(wa[6], hbv[2], gz1);  gz1 = MFMA16(wa[7], hbv[3], gz1);
        gn0 = MFMA16(wa[8], hbv[0], gn0);  gn0 = MFMA16(wa[9], hbv[1], gn0);
        gn1 = MFMA16(wa[10], hbv[2], gn1); gn1 = MFMA16(wa[11], hbv[3], gn1);
        float gir[4], giz[4], gin[4];
        bf2x2(gcur[0].x, gir[0], gir[1]); bf2x2(gcur[0].y, gir[2], gir[3]);
        bf2x2(gcur[1].x, giz[0], giz[1]); bf2x2(gcur[1].y, giz[2], giz[3]);
        bf2x2(gcur[2].x, gin[0], gin[1]); bf2x2(gcur[2].y, gin[2], gin[3]);
        float hpv[4];
        #pragma unroll
        for (int r = 0; r < 4; r++) {
            const float rr = sigmoidf_(gir[r] + (gr0[r] + gr1[r]) + sbr[r]);
            const float zz = sigmoidf_(giz[r] + (gz0[r] + gz1[r]) + sbz[r]);
            const float nn = tanhf_(gin[r] + rr * ((gn0[r] + gn1[r]) + bhn[r]));
            const float hn = (1.f - zz) * nn + zz * hst[r];
            hst[r] = hn; hpv[r] = hn;
        }
        uint2 hw2;
        hw2.x = packbf(hpv[0], hpv[1]);
        hw2.y = packbf(hpv[2], hpv[3]);
        *(uint2*)&hbuf[cur ^ 1][u * HS + w * 16 + q * 4] = hw2;
        *(uint2*)(hp + (size_t)t * 2048) = hw2;      // coalesced 512B/wave
        gcur[0] = gnxt[0]; gcur[1] = gnxt[1]; gcur[2] = gnxt[2];
        gnxt[0] = g2s[0];  gnxt[1] = g2s[1];  gnxt[2] = g2s[2];
        ldsbar();
    }
}

// ---------------- K4: k_dot — LN2 + pos/neg dots, fully parallel ----------------
__global__ __launch_bounds__(256) void k_dot(const int* __restrict__ seqs,
                                             const int* __restrict__ negs,
                                             const u16* __restrict__ hseq2,
                                             const u16* __restrict__ embT,
                                             const void* __restrict__ g2,
                                             const void* __restrict__ b2,
                                             void* __restrict__ out,
                                             const int* __restrict__ flag) {
    const int dt = *flag;
    const int m = blockIdx.x * 4 + (threadIdx.x >> 6);
    const int L = threadIdx.x & 63;
    const int b = m / T_, t = m - b * T_;
    const int grp = b >> 4, bi = b & 15;
    const size_t hoff = (size_t)(grp * T_ + t) * 2048
                      + (size_t)(L >> 3) * 256 + ((L >> 1) & 3) * 64 + bi * 4 + (L & 1) * 2;
    const u32 hh = *(const u32*)&hseq2[hoff];
    float h0, h1; bf2x2(hh, h0, h1);
    float s1 = h0 + h1, s2 = h0 * h0 + h1 * h1;
    #pragma unroll
    for (int o = 1; o <= 32; o <<= 1) {
        s1 += __shfl_xor(s1, o, 64);
        s2 += __shfl_xor(s2, o, 64);
    }
    const float mu = s1 * (1.0f / H_);
    const float rs = rsqrtf(s2 * (1.0f / H_) - mu * mu + 1e-8f);
    float gv0, gv1, bv0, bv1;
    if (dt) {
        const float2 g = ((const float2*)g2)[L];
        const float2 bb = ((const float2*)b2)[L];
        gv0 = g.x; gv1 = g.y; bv0 = bb.x; bv1 = bb.y;
    } else {
        bf2x2(((const u32*)g2)[L], gv0, gv1);
        bf2x2(((const u32*)b2)[L], bv0, bv1);
    }
    const float lo0 = (h0 - mu) * rs * gv0 + bv0;
    const float lo1 = (h1 - mu) * rs * gv1 + bv1;
    const int ptok = seqs[b * L_ + t + 1];
    const int ntok = negs[b * L_ + t + 1];
    const u32 pp = *(const u32*)&embT[(size_t)ptok * H_ + L * 2];
    const u32 nn = *(const u32*)&embT[(size_t)ntok * H_ + L * 2];
    float p0, p1, n0, n1; bf2x2(pp, p0, p1); bf2x2(nn, n0, n1);
    float pe = lo0 * p0 + lo1 * p1;
    float ne = lo0 * n0 + lo1 * n1;
    #pragma unroll
    for (int o = 1; o <= 32; o <<= 1) {
        pe += __shfl_xor(pe, o, 64);
        ne += __shfl_xor(ne, o, 64);
    }
    if (L == 0) {
        if (dt) {
            ((float*)out)[m]      = pe;
            ((float*)out)[M_ + m] = ne;
        } else {
            ((u16*)out)[m]        = f2bf(pe);
            ((u16*)out)[M_ + m]   = f2bf(ne);
        }
    }
}

extern "C" void kernel_launch(void* const* d_in, const int* in_sizes, int n_in,
                              void* d_out, int out_size, void* d_ws, size_t ws_size,
                              hipStream_t stream) {
    const int* seqs = (const int*)d_in[0];
    const int* negs = (const int*)d_in[1];
    const void* embW = d_in[2];
    const void* Wih  = d_in[3];
    const void* Whh  = d_in[4];
    const void* bih  = d_in[5];
    const void* bhh  = d_in[6];
    const void* g1   = d_in[7];
    const void* b1   = d_in[8];
    const void* g2   = d_in[9];
    const void* b2   = d_in[10];

    char* ws = (char*)d_ws;
    int* flag = (int*)ws;
    u16* embT  = (u16*)(ws + OFF_EMBT);
    u16* gi2   = (u16*)(ws + OFF_GI);
    u16* hseq2 = (u16*)(ws + OFF_HSEQ);

    k_sniff<<<1, 64, 0, stream>>>((const u32*)embW, flag);
    k_transpose<<<dim3((V_ + 31) / 32, H_ / 32), dim3(32, 32), 0, stream>>>(embW, embT, flag);
    k_gi<<<M_ / 64, 256, 0, stream>>>(seqs, embT, g1, b1, Wih, bih, gi2, flag);
    k_rec<<<NBLK, 512, 0, stream>>>(gi2, Whh, bhh, hseq2, flag);
    k_dot<<<M_ / 4, 256, 0, stream>>>(seqs, negs, hseq2, embT, g2, b2, d_out, flag);
}

// Round 10
// 360.608 us; speedup vs baseline: 1.5692x; 1.0572x over previous
//
#include <hip/hip_runtime.h>

typedef unsigned int u32;
typedef unsigned short u16;
typedef __attribute__((ext_vector_type(8))) short bf16x8;
typedef __attribute__((ext_vector_type(4))) float f32x4;

#define B_   512
#define L_   201
#define T_   200
#define H_   128
#define V_   100001
#define G3_  384
#define M_   (B_*T_)         // 102400
#define GPB  16              // batches per recurrence block
#define NBLK (B_/GPB)        // 32 blocks
#define HS   136             // LDS row stride in u16 (>=128!), 272B, 16B-aligned

// ws layout (bytes):
//   [0,256) flag | [256,+25.6MB) embT | [25600768,+78.6MB) gi2 | [104243968,+26.2MB) hseq2
// gi2  (wave-major): off_u16 = (grp*T+t)*6144 + g*2048 + w*256 + q*64 + u*4
// hseq2(wave-major): off_u16 = (grp*T+t)*2048 +           w*256 + q*64 + u*4
//   i.e. h[i=w8*16+q*4+r][b=grp*16+u] at (grp*T+t)*2048 + w8*256 + q*64 + u*4 + r
#define OFF_EMBT 256
#define OFF_GI   25600768ull
#define OFF_HSEQ 104243968ull

__device__ __forceinline__ float bf2f(u16 a) {
    return __uint_as_float(((u32)a) << 16);
}
__device__ __forceinline__ void bf2x2(u32 p, float& lo, float& hi) {
    lo = __uint_as_float(p << 16);
    hi = __uint_as_float(p & 0xffff0000u);
}
__device__ __forceinline__ u16 f2bf(float f) {
    u32 u = __float_as_uint(f);
    u32 lsb = (u >> 16) & 1u;
    u += 0x7fffu + lsb;   // RNE
    return (u16)(u >> 16);
}
__device__ __forceinline__ u32 packbf(float a, float b) {
#if __has_builtin(__builtin_amdgcn_cvt_pk_bf16_f32)
    typedef __attribute__((ext_vector_type(2))) __bf16 bf16x2_t;
    bf16x2_t r = __builtin_amdgcn_cvt_pk_bf16_f32(a, b);
    return *(u32*)&r;
#else
    return (u32)f2bf(a) | ((u32)f2bf(b) << 16);
#endif
}
__device__ __forceinline__ float frcp(float x) {
    return __builtin_amdgcn_rcpf(x);
}
__device__ __forceinline__ float sigmoidf_(float x) {
    return frcp(1.0f + __expf(-x));
}
__device__ __forceinline__ float tanhf_(float x) {
    return fmaf(-2.0f, frcp(__expf(2.0f * x) + 1.0f), 1.0f);
}
__device__ __forceinline__ void halfred2(float& a, float& b) {
    #pragma unroll
    for (int o = 1; o <= 16; o <<= 1) {
        a += __shfl_xor(a, o, 64);
        b += __shfl_xor(b, o, 64);
    }
}
__device__ __forceinline__ float ldv(const void* p, int dt, int i) {
    return dt ? ((const float*)p)[i] : bf2f(((const u16*)p)[i]);
}
// LDS-only barrier: waits ds ops but does NOT drain vmcnt.
__device__ __forceinline__ void ldsbar() {
    asm volatile("s_waitcnt lgkmcnt(0)\n\ts_barrier" ::: "memory");
}
__device__ __forceinline__ bf16x8 load_frag(const void* W, int dt, int row, int koff) {
    union { bf16x8 v; u32 uu[4]; uint4 q; } r;
    if (dt) {
        const float4* p = (const float4*)((const float*)W + (size_t)row * H_ + koff);
        const float4 a = p[0], b = p[1];
        r.uu[0] = packbf(a.x, a.y); r.uu[1] = packbf(a.z, a.w);
        r.uu[2] = packbf(b.x, b.y); r.uu[3] = packbf(b.z, b.w);
    } else {
        r.q = *(const uint4*)((const u16*)W + (size_t)row * H_ + koff);
    }
    return r.v;
}
#define MFMA16(a, b, c) __builtin_amdgcn_mfma_f32_16x16x32_bf16((a), (b), (c), 0, 0, 0)

// ---------------- K0: dtype sniffer --------------------------------------------
__global__ __launch_bounds__(64) void k_sniff(const u32* __restrict__ raw,
                                              int* __restrict__ flag) {
    const int lane = threadIdx.x;
    int big = 0;
    #pragma unroll
    for (int i = 0; i < 16; i++) {
        const u32 w = raw[lane * 16 + i];
        float lo, hi; bf2x2(w, lo, hi);
        if (!(fabsf(lo) <= 16.0f)) big++;
        if (!(fabsf(hi) <= 16.0f)) big++;
    }
    #pragma unroll
    for (int o = 32; o >= 1; o <<= 1) big += __shfl_xor(big, o, 64);
    if (lane == 0) *flag = (big > 8) ? 1 : 0;
}

// ---------------- K1: transpose emb_W (H,V) -> embT (V,H) bf16 ------------------
__global__ __launch_bounds__(1024) void k_transpose(const void* __restrict__ embW,
                                                    u16* __restrict__ embT,
                                                    const int* __restrict__ flag) {
    const int dt = *flag;
    __shared__ u16 tile[32][33];
    const int v0 = blockIdx.x * 32;
    const int h0 = blockIdx.y * 32;
    const int tx = threadIdx.x, ty = threadIdx.y;
    const int v = v0 + tx, h = h0 + ty;
    if (v < V_) {
        u16 val;
        if (dt) val = f2bf(((const float*)embW)[(size_t)h * V_ + v]);
        else    val = ((const u16*)embW)[(size_t)h * V_ + v];
        tile[ty][tx] = val;
    }
    __syncthreads();
    const int vo = v0 + ty, ho = h0 + tx;
    if (vo < V_) embT[(size_t)vo * H_ + ho] = tile[tx][ty];
}

// ---------------- K2: k_gi — gather + LN1 + (gi = x @ Wih^T + bih), MFMA --------
// 1600 blocks x 256 threads. Block tile = 16 batches x 4 timesteps; gi2 store is
// one contiguous 512B/wave transaction (k_rec's layout).
__global__ __launch_bounds__(256) void k_gi(const int* __restrict__ seqs,
                                            const u16* __restrict__ embT,
                                            const void* __restrict__ g1,
                                            const void* __restrict__ b1,
                                            const void* __restrict__ Wih,
                                            const void* __restrict__ bih,
                                            u16* __restrict__ gi2,
                                            const int* __restrict__ flag) {
    const int dt = *flag;
    __shared__ u16 xs[64 * HS];
    const int tid = threadIdx.x;
    const int w = tid >> 6, L = tid & 63;
    const int q = L >> 4, u = L & 15;
    const int lk = L & 31;
    const int hw = w * 2 + (L >> 5);
    const int grp = blockIdx.x / 50;
    const int tc  = blockIdx.x % 50;
    float g1v[4], b1v[4];
    #pragma unroll
    for (int j = 0; j < 4; j++) {
        g1v[j] = ldv(g1, dt, lk * 4 + j);
        b1v[j] = ldv(b1, dt, lk * 4 + j);
    }
    #pragma unroll
    for (int it = 0; it < 8; it++) {
        const int row = hw * 8 + it;
        const int s = row >> 4, bi = row & 15;
        const int b = grp * GPB + bi;
        const int t = tc * 4 + s;
        const int tok = seqs[b * L_ + t];
        const uint2 e = *(const uint2*)&embT[(size_t)tok * H_ + lk * 4];
        float f0, f1, f2, f3; bf2x2(e.x, f0, f1); bf2x2(e.y, f2, f3);
        float s1 = (f0 + f1) + (f2 + f3);
        float s2 = (f0*f0 + f1*f1) + (f2*f2 + f3*f3);
        halfred2(s1, s2);
        const float mu = s1 * (1.0f / H_);
        const float rs = rsqrtf(s2 * (1.0f / H_) - mu * mu + 1e-8f);
        uint2 xw;
        xw.x = packbf((f0-mu)*rs*g1v[0]+b1v[0], (f1-mu)*rs*g1v[1]+b1v[1]);
        xw.y = packbf((f2-mu)*rs*g1v[2]+b1v[2], (f3-mu)*rs*g1v[3]+b1v[3]);
        *(uint2*)&xs[row * HS + lk * 4] = xw;
    }
    bf16x8 af[6][4];
    float bb[6][4];
    #pragma unroll
    for (int j = 0; j < 6; j++) {
        const int nt = w * 6 + j;
        #pragma unroll
        for (int c = 0; c < 4; c++)
            af[j][c] = load_frag(Wih, dt, nt * 16 + u, c * 32 + q * 8);
        if (dt) {
            const float4 bv = *(const float4*)((const float*)bih + nt * 16 + q * 4);
            bb[j][0] = bv.x; bb[j][1] = bv.y; bb[j][2] = bv.z; bb[j][3] = bv.w;
        } else {
            const uint2 bv = *(const uint2*)((const u16*)bih + nt * 16 + q * 4);
            bf2x2(bv.x, bb[j][0], bb[j][1]); bf2x2(bv.y, bb[j][2], bb[j][3]);
        }
    }
    ldsbar();
    #pragma unroll
    for (int s = 0; s < 4; s++) {
        bf16x8 xbv[4];
        #pragma unroll
        for (int c = 0; c < 4; c++)
            xbv[c] = *(const bf16x8*)&xs[(s * 16 + u) * HS + c * 32 + q * 8];
        const int t = tc * 4 + s;
        const size_t base_t = (size_t)(grp * T_ + t) * 6144 + q * 64 + u * 4;
        #pragma unroll
        for (int j = 0; j < 6; j++) {
            const int nt = w * 6 + j;
            f32x4 C = {0.f, 0.f, 0.f, 0.f};
            #pragma unroll
            for (int c = 0; c < 4; c++) C = MFMA16(af[j][c], xbv[c], C);
            uint2 o;
            o.x = packbf(C[0] + bb[j][0], C[1] + bb[j][1]);
            o.y = packbf(C[2] + bb[j][2], C[3] + bb[j][3]);
            *(uint2*)&gi2[base_t + (nt >> 3) * 2048 + (nt & 7) * 256] = o;
        }
    }
}

// ---------------- K3: k_rec — slim persistent GRU recurrence --------------------
// 32 blocks x 512 threads. bhh biases folded into MFMA C-init (C rows are
// lane-constant per reg slot — exactly where the bias lands).
__global__ __launch_bounds__(512, 2) void k_rec(const u16* __restrict__ gi2,
                                                const void* __restrict__ Whh,
                                                const void* __restrict__ bhh,
                                                u16* __restrict__ hseq2,
                                                const int* __restrict__ flag) {
    const int dt = *flag;
    __shared__ u16 hbuf[2][GPB * HS];
    const int tid = threadIdx.x;
    const int w = tid >> 6, L = tid & 63;
    const int q = L >> 4, u = L & 15;
    const int grp = blockIdx.x;
    for (int i = tid; i < GPB * HS; i += 512) hbuf[0][i] = 0;
    bf16x8 wa[12];
    #pragma unroll
    for (int g = 0; g < 3; g++)
        #pragma unroll
        for (int c = 0; c < 4; c++)
            wa[g * 4 + c] = load_frag(Whh, dt, g * H_ + w * 16 + u, c * 32 + q * 8);
    f32x4 sbr, sbz, sbn;
    #pragma unroll
    for (int r = 0; r < 4; r++) {
        const int i = w * 16 + q * 4 + r;
        sbr[r] = ldv(bhh, dt, i);
        sbz[r] = ldv(bhh, dt, H_ + i);
        sbn[r] = ldv(bhh, dt, 2 * H_ + i);
    }
    float hst[4] = {0.f, 0.f, 0.f, 0.f};
    const u16* gp = gi2 + (size_t)grp * T_ * 6144 + (size_t)w * 256 + q * 64 + u * 4;
    u16* hp = hseq2 + (size_t)grp * T_ * 2048 + (size_t)w * 256 + q * 64 + u * 4;
    uint2 gcur[3], gnxt[3];
    #pragma unroll
    for (int g = 0; g < 3; g++) {
        gcur[g] = *(const uint2*)(gp + 0 * 6144 + g * 2048);
        gnxt[g] = *(const uint2*)(gp + 1 * 6144 + g * 2048);
    }
    ldsbar();
    for (int t = 0; t < T_; t++) {
        const int cur = t & 1;
        const int tpre = (t + 2 < T_) ? (t + 2) : (T_ - 1);
        uint2 g2s[3];
        #pragma unroll
        for (int g = 0; g < 3; g++)
            g2s[g] = *(const uint2*)(gp + (size_t)tpre * 6144 + g * 2048);
        bf16x8 hbv[4];
        #pragma unroll
        for (int c = 0; c < 4; c++)
            hbv[c] = *(const bf16x8*)&hbuf[cur][u * HS + c * 32 + q * 8];
        f32x4 z4 = {0.f, 0.f, 0.f, 0.f};
        // bias folded into C-init of the first chain of each gate
        f32x4 gr0 = sbr, gr1 = z4, gz0 = sbz, gz1 = z4, gn0 = sbn, gn1 = z4;
        gr0 = MFMA16(wa[0], hbv[0], gr0);  gr0 = MFMA16(wa[1], hbv[1], gr0);
        gr1 = MFMA16(wa[2], hbv[2], gr1);  gr1 = MFMA16(wa[3], hbv[3], gr1);
        gz0 = MFMA16(wa[4], hbv[0], gz0);  gz0 = MFMA16(wa[5], hbv[1], gz0);
        gz1 = MFMA16(wa[6], hbv[2], gz1);  gz1 = MFMA16(wa[7], hbv[3], gz1);
        gn0 = MFMA16(wa[8], hbv[0], gn0);  gn0 = MFMA16(wa[9], hbv[1], gn0);
        gn1 = MFMA16(wa[10], hbv[2], gn1); gn1 = MFMA16(wa[11], hbv[3], gn1);
        float gir[4], giz[4], gin[4];
        bf2x2(gcur[0].x, gir[0], gir[1]); bf2x2(gcur[0].y, gir[2], gir[3]);
        bf2x2(gcur[1].x, giz[0], giz[1]); bf2x2(gcur[1].y, giz[2], giz[3]);
        bf2x2(gcur[2].x, gin[0], gin[1]); bf2x2(gcur[2].y, gin[2], gin[3]);
        float hpv[4];
        #pragma unroll
        for (int r = 0; r < 4; r++) {
            const float rr = sigmoidf_(gir[r] + (gr0[r] + gr1[r]));
            const float zz = sigmoidf_(giz[r] + (gz0[r] + gz1[r]));
            const float nn = tanhf_(fmaf(rr, gn0[r] + gn1[r], gin[r]));
            const float hn = fmaf(zz, hst[r] - nn, nn);
            hst[r] = hn; hpv[r] = hn;
        }
        uint2 hw2;
        hw2.x = packbf(hpv[0], hpv[1]);
        hw2.y = packbf(hpv[2], hpv[3]);
        *(uint2*)&hbuf[cur ^ 1][u * HS + w * 16 + q * 4] = hw2;
        *(uint2*)(hp + (size_t)t * 2048) = hw2;
        gcur[0] = gnxt[0]; gcur[1] = gnxt[1]; gcur[2] = gnxt[2];
        gnxt[0] = g2s[0];  gnxt[1] = g2s[1];  gnxt[2] = g2s[2];
        ldsbar();
    }
}

// ---------------- K4: k_dot — LN2 + pos/neg dots, one wave per (grp,t) ----------
// Lane (q=L>>4, u=L&15) holds h[i = j*16 + q*4 + r][b = grp*16+u] for j=0..7 —
// read as 8 coalesced uint2 loads of k_rec's chunk. Reductions are cross-quad
// only (shfl_xor 16,32). 16 (b,t) outputs per wave.
__global__ __launch_bounds__(256) void k_dot(const int* __restrict__ seqs,
                                             const int* __restrict__ negs,
                                             const u16* __restrict__ hseq2,
                                             const u16* __restrict__ embT,
                                             const void* __restrict__ g2,
                                             const void* __restrict__ b2,
                                             void* __restrict__ out,
                                             const int* __restrict__ flag) {
    const int dt = *flag;
    const int wid = threadIdx.x >> 6;
    const int L = threadIdx.x & 63;
    const int q = L >> 4, u = L & 15;
    const int grp = blockIdx.x / 50;
    const int t   = (blockIdx.x % 50) * 4 + wid;
    const int b   = grp * GPB + u;
    // h chunk: 8 coalesced uint2 loads
    const u16* hc = hseq2 + (size_t)(grp * T_ + t) * 2048;
    uint2 hv[8];
    #pragma unroll
    for (int j = 0; j < 8; j++)
        hv[j] = *(const uint2*)&hc[j * 256 + L * 4];
    // tokens (4 lanes share each address -> HW broadcast)
    const int ptok = seqs[b * L_ + t + 1];
    const int ntok = negs[b * L_ + t + 1];
    // LN2 stats over i for batch u
    float hf[8][4];
    float s1 = 0.f, s2 = 0.f;
    #pragma unroll
    for (int j = 0; j < 8; j++) {
        float a0, a1, a2, a3;
        bf2x2(hv[j].x, a0, a1); bf2x2(hv[j].y, a2, a3);
        hf[j][0] = a0; hf[j][1] = a1; hf[j][2] = a2; hf[j][3] = a3;
        s1 += (a0 + a1) + (a2 + a3);
        s2 += (a0*a0 + a1*a1) + (a2*a2 + a3*a3);
    }
    s1 += __shfl_xor(s1, 16, 64); s2 += __shfl_xor(s2, 16, 64);
    s1 += __shfl_xor(s1, 32, 64); s2 += __shfl_xor(s2, 32, 64);
    const float mu = s1 * (1.0f / H_);
    const float rs = rsqrtf(s2 * (1.0f / H_) - mu * mu + 1e-8f);
    // dots
    float pe = 0.f, ne = 0.f;
    #pragma unroll
    for (int j = 0; j < 8; j++) {
        const int io = j * 16 + q * 4;
        float gv0, gv1, gv2, gv3, bv0, bv1, bv2, bv3;
        if (dt) {
            const float4 g = *(const float4*)((const float*)g2 + io);
            const float4 bbv = *(const float4*)((const float*)b2 + io);
            gv0 = g.x; gv1 = g.y; gv2 = g.z; gv3 = g.w;
            bv0 = bbv.x; bv1 = bbv.y; bv2 = bbv.z; bv3 = bbv.w;
        } else {
            const uint2 g = *(const uint2*)((const u16*)g2 + io);
            const uint2 bbv = *(const uint2*)((const u16*)b2 + io);
            bf2x2(g.x, gv0, gv1); bf2x2(g.y, gv2, gv3);
            bf2x2(bbv.x, bv0, bv1); bf2x2(bbv.y, bv2, bv3);
        }
        const uint2 pp = *(const uint2*)&embT[(size_t)ptok * H_ + io];
        const uint2 nn = *(const uint2*)&embT[(size_t)ntok * H_ + io];
        float p0, p1, p2, p3, n0, n1, n2, n3;
        bf2x2(pp.x, p0, p1); bf2x2(pp.y, p2, p3);
        bf2x2(nn.x, n0, n1); bf2x2(nn.y, n2, n3);
        const float lo0 = fmaf((hf[j][0] - mu) * rs, gv0, bv0);
        const float lo1 = fmaf((hf[j][1] - mu) * rs, gv1, bv1);
        const float lo2 = fmaf((hf[j][2] - mu) * rs, gv2, bv2);
        const float lo3 = fmaf((hf[j][3] - mu) * rs, gv3, bv3);
        pe += (lo0*p0 + lo1*p1) + (lo2*p2 + lo3*p3);
        ne += (lo0*n0 + lo1*n1) + (lo2*n2 + lo3*n3);
    }
    pe += __shfl_xor(pe, 16, 64); ne += __shfl_xor(ne, 16, 64);
    pe += __shfl_xor(pe, 32, 64); ne += __shfl_xor(ne, 32, 64);
    if (q == 0) {
        const int m = b * T_ + t;
        if (dt) {
            ((float*)out)[m]      = pe;
            ((float*)out)[M_ + m] = ne;
        } else {
            ((u16*)out)[m]        = f2bf(pe);
            ((u16*)out)[M_ + m]   = f2bf(ne);
        }
    }
}

extern "C" void kernel_launch(void* const* d_in, const int* in_sizes, int n_in,
                              void* d_out, int out_size, void* d_ws, size_t ws_size,
                              hipStream_t stream) {
    const int* seqs = (const int*)d_in[0];
    const int* negs = (const int*)d_in[1];
    const void* embW = d_in[2];
    const void* Wih  = d_in[3];
    const void* Whh  = d_in[4];
    const void* bih  = d_in[5];
    const void* bhh  = d_in[6];
    const void* g1   = d_in[7];
    const void* b1   = d_in[8];
    const void* g2   = d_in[9];
    const void* b2   = d_in[10];

    char* ws = (char*)d_ws;
    int* flag = (int*)ws;
    u16* embT  = (u16*)(ws + OFF_EMBT);
    u16* gi2   = (u16*)(ws + OFF_GI);
    u16* hseq2 = (u16*)(ws + OFF_HSEQ);

    k_sniff<<<1, 64, 0, stream>>>((const u32*)embW, flag);
    k_transpose<<<dim3((V_ + 31) / 32, H_ / 32), dim3(32, 32), 0, stream>>>(embW, embT, flag);
    k_gi<<<M_ / 64, 256, 0, stream>>>(seqs, embT, g1, b1, Wih, bih, gi2, flag);
    k_rec<<<NBLK, 512, 0, stream>>>(gi2, Whh, bhh, hseq2, flag);
    k_dot<<<M_ / 64, 256, 0, stream>>>(seqs, negs, hseq2, embT, g2, b2, d_out, flag);
}